// Round 4
// baseline (578.695 us; speedup 1.0000x reference)
//
#include <hip/hip_runtime.h>
#include <hip/hip_bf16.h>

// IrrepLinear: out[b, o*25+m] = sum_i x[b, i*25+m] * W[l(m), o, i]  (+bias at m=0)
// Block = 16 b-rows x 64 o-cols x all 25 m. 5 waves = 5 m-groups; each wave owns
// all 4 o-frags (4x A-frag reuse). Single-buffer LDS 32000B -> 5 blocks/CU (25
// waves, 78%); latency hiding is cross-block, not intra-block.
// LDS layout row=b*25+m, pitch 80B: write lanes (dm=1 -> +20 words mod 32) and
// read lanes (dlr -> +500 = 20 mod 32) both cycle all 8 granule starts =>
// conflict-free by construction (r2's 3.3e7 conflicts were d(addr) = 0 mod 32).

typedef __bf16 bf16x8v __attribute__((ext_vector_type(8)));
typedef float floatx4 __attribute__((ext_vector_type(4)));
typedef unsigned short ushort_t;
typedef unsigned short ushortx4 __attribute__((ext_vector_type(4)));

#define ROW_F 12800          // floats per batch row (512*25)
#define PITCH 40             // ushorts per LDS row (80B, 16B-aligned octets)
#define LDS_USH (400 * 40)   // 32000 B

__device__ __forceinline__ ushort_t f2bf(float f) {
    __hip_bfloat16 h = __float2bfloat16(f);   // RNE
    return __builtin_bit_cast(ushort_t, h);
}

// weight fp32 [5][512][512] -> bf16 in ws (same layout, k=i contiguous)
__global__ void cvt_w_kernel(const float* __restrict__ w, ushort_t* __restrict__ wb) {
    int i = (blockIdx.x * 256 + threadIdx.x) * 4;   // 1310720 elems, 1280x256 exact
    floatx4 v = *reinterpret_cast<const floatx4*>(w + i);
    ushortx4 h;
    h.x = f2bf(v[0]); h.y = f2bf(v[1]); h.z = f2bf(v[2]); h.w = f2bf(v[3]);
    *reinterpret_cast<ushortx4*>(wb + i) = h;
}

__global__ __launch_bounds__(320) void irrep_kernel(
        const float* __restrict__ x, const ushort_t* __restrict__ wb,
        const float* __restrict__ bias, float* __restrict__ out) {
    __shared__ __align__(16) ushort_t Asm[LDS_USH];

    const int tid = threadIdx.x, lane = tid & 63;
    const int g  = tid >> 6;          // wave = m-group: m in [g*5, g*5+5)
    const int lr = lane & 15, lh = lane >> 4;

    // XCD swizzle: the 8 o-siblings of a b-tile get bids with equal bid%8
    // (same XCD under round-robin) -> x-tile fetched from HBM once per XCD.
    const int bid = blockIdx.x;                       // 2048 blocks
    const int swz = ((bid & 7) << 8) | (bid >> 3);    // bijective on [0,2048)
    const int btile = swz >> 3, osib = swz & 7;
    const int b0 = btile * 16, o0 = osib * 64;

    // ---- staging quads: Q = tid + 320*i, Q = bb*200 + kq*25 + m (m fastest ->
    // global loads lane-contiguous in 25-float runs; LDS writes spread banks).
    unsigned goff[10]; int woff[10];
#pragma unroll
    for (int i = 0; i < 10; ++i) {
        int Q = tid + 320 * i;
        int bb = Q / 200, r = Q - bb * 200;
        int kq = r / 25, m = r - kq * 25;
        goff[i] = (unsigned)(((b0 + bb) * ROW_F + kq * 100 + m) * 4);  // bytes
        woff[i] = (bb * 25 + m) * PITCH + kq * 4;                      // ushorts
    }

    float vbuf[10][4];
    auto issue = [&](int s) {      // x loads for step s -> regs (hidden under compute)
#pragma unroll
        for (int i = 0; i < 10; ++i) {
            const float* p = (const float*)((const char*)x + goff[i] + s * 3200);
#pragma unroll
            for (int j = 0; j < 4; ++j) vbuf[i][j] = p[j * 25];
        }
    };
    auto scat = [&]() {            // 10 x ds_write_b64, conflict-free
#pragma unroll
        for (int i = 0; i < 10; ++i) {
            ushortx4 h;
#pragma unroll
            for (int j = 0; j < 4; ++j) h[j] = f2bf(vbuf[i][j]);
            *reinterpret_cast<ushortx4*>(&Asm[woff[i]]) = h;
        }
    };

    // B-frag byte offsets (of=0), per mm; +of*16384, +s*64 at use.
    unsigned offB[5];
#pragma unroll
    for (int mm = 0; mm < 5; ++mm) {
        int m = g * 5 + mm;
        int l = (m >= 1) + (m >= 4) + (m >= 9) + (m >= 16);   // floor(sqrt(m))
        offB[mm] = (unsigned)((((l * 512 + o0 + lr) * 512) + lh * 8) * 2);
    }

    floatx4 acc[5][4];   // [mm][of]
#pragma unroll
    for (int mm = 0; mm < 5; ++mm)
#pragma unroll
        for (int of = 0; of < 4; ++of) acc[mm][of] = (floatx4){0.f, 0.f, 0.f, 0.f};

    issue(0);
    const char* wbb = (const char*)wb;

#pragma unroll 1
    for (int s = 0; s < 16; ++s) {
        __syncthreads();                 // previous step's A-reads done
        scat();                          // waits vbuf vmcnt internally
        __syncthreads();                 // tile ready
        if (s < 15) issue(s + 1);

        bf16x8v afr[5];
#pragma unroll
        for (int mm = 0; mm < 5; ++mm)
            afr[mm] = *reinterpret_cast<const bf16x8v*>(
                &Asm[(lr * 25 + g * 5 + mm) * PITCH + lh * 8]);

        // two o-halves to cap live B-frag registers at 40
#pragma unroll
        for (int oh = 0; oh < 2; ++oh) {
            bf16x8v bfr[5][2];
#pragma unroll
            for (int mm = 0; mm < 5; ++mm)
#pragma unroll
                for (int oo = 0; oo < 2; ++oo)
                    bfr[mm][oo] = *reinterpret_cast<const bf16x8v*>(
                        wbb + offB[mm] + (oh * 2 + oo) * 16384 + s * 64);
#pragma unroll
            for (int mm = 0; mm < 5; ++mm)
#pragma unroll
                for (int oo = 0; oo < 2; ++oo)
                    acc[mm][oh * 2 + oo] = __builtin_amdgcn_mfma_f32_16x16x32_bf16(
                        afr[mm], bfr[mm][oo], acc[mm][oh * 2 + oo], 0, 0, 0);
        }
    }

    // bias on m=0 only (g==0 wave-uniform)
    if (g == 0) {
#pragma unroll
        for (int of = 0; of < 4; ++of) {
            float bv = bias[o0 + of * 16 + lr];
#pragma unroll
            for (int r = 0; r < 4; ++r) acc[0][of][r] += bv;
        }
    }

    // direct-scatter epilogue: 5 consecutive floats per (of,r); all (o,m) lines
    // in the block's 6.4KB/row range are fully covered -> L2 write-combines.
    // D layout: col = lane&15 (o), row = (lane>>4)*4 + r (b).
#pragma unroll
    for (int of = 0; of < 4; ++of)
#pragma unroll
        for (int r = 0; r < 4; ++r) {
            float* op = out + (size_t)(b0 + lh * 4 + r) * ROW_F
                            + (o0 + of * 16 + lr) * 25 + g * 5;
            op[0] = acc[0][of][r]; op[1] = acc[1][of][r]; op[2] = acc[2][of][r];
            op[3] = acc[3][of][r]; op[4] = acc[4][of][r];
        }
}

extern "C" void kernel_launch(void* const* d_in, const int* in_sizes, int n_in,
                              void* d_out, int out_size, void* d_ws, size_t ws_size,
                              hipStream_t stream) {
    const float* x    = (const float*)d_in[0];
    const float* w    = (const float*)d_in[1];
    const float* bias = (const float*)d_in[2];
    float* outp       = (float*)d_out;
    ushort_t* wb      = (ushort_t*)d_ws;    // 2.62 MB bf16 weights

    cvt_w_kernel<<<1280, 256, 0, stream>>>(w, wb);
    irrep_kernel<<<2048, 320, 0, stream>>>(x, wb, bias, outp);
}

// Round 5
// 293.590 us; speedup vs baseline: 1.9711x; 1.9711x over previous
//
#include <hip/hip_runtime.h>
#include <hip/hip_bf16.h>

// IrrepLinear: out[b, o*25+m] = sum_i x[b, i*25+m] * W[l(m), o, i]  (+bias at m=0)
// r5: wave = all-25-m x 16-o (l-dedup: 5 B-frags/wave/step -> B-L2 655MB, the
// r3/r4 regressions were 2-3.3GB of B-frag L2 traffic). Block = 4 waves = 16b x
// 64o x 25m, 2048 blocks, single 32KB LDS buffer -> >=2 independent blocks/CU.
// LDS row = bb*25+m, pitch 80B (reads balanced 8 lanes/16B-slot = conflict-free;
// writes <=2-way). Staging: 4 same-m k-consecutive scalars -> 1 ds_write_b64.

typedef __bf16 bf16x8v __attribute__((ext_vector_type(8)));
typedef float floatx4 __attribute__((ext_vector_type(4)));
typedef unsigned short ushort_t;
typedef unsigned short ushortx4 __attribute__((ext_vector_type(4)));

#define ROW_F 12800          // floats per batch row (512*25)
#define PITCH 40             // ushorts per LDS row: 32 k-data + 8 pad (80B)
#define LDS_USH (400 * 40)   // 32000 B

__device__ __forceinline__ ushort_t f2bf(float f) {
    __hip_bfloat16 h = __float2bfloat16(f);   // RNE
    return __builtin_bit_cast(ushort_t, h);
}

// weight fp32 [5][512][512] -> bf16 in ws (same layout, k contiguous)
__global__ void cvt_w_kernel(const float* __restrict__ w, ushort_t* __restrict__ wb) {
    int i = (blockIdx.x * 256 + threadIdx.x) * 4;   // 1310720 elems, 1280x256 exact
    floatx4 v = *reinterpret_cast<const floatx4*>(w + i);
    ushortx4 h;
    h.x = f2bf(v[0]); h.y = f2bf(v[1]); h.z = f2bf(v[2]); h.w = f2bf(v[3]);
    *reinterpret_cast<ushortx4*>(wb + i) = h;
}

__global__ __launch_bounds__(256, 2) void irrep_kernel(
        const float* __restrict__ x, const ushort_t* __restrict__ wb,
        const float* __restrict__ bias, float* __restrict__ out) {
    __shared__ __align__(16) ushort_t Asm[LDS_USH];

    const int tid = threadIdx.x, lane = tid & 63;
    const int wv = tid >> 6;                  // 4 waves = 4 o-slices of 16
    const int lr = lane & 15, lh = lane >> 4;

    // osib = bid>>8: the 8 o-siblings of a btile have equal bid%8 -> same XCD
    // under round-robin -> x window fetched from HBM once, siblings L2-hit.
    const int bid = blockIdx.x;               // 2048 blocks
    const int osib = bid >> 8, btile = bid & 255;
    const int b0 = btile * 16, o0 = osib * 64, ow = o0 + wv * 16;

    constexpr int LOF[25] = {0,1,1,1,2,2,2,2,2,3,3,3,3,3,3,3,4,4,4,4,4,4,4,4,4};

    // ---- staging quads: Q = bb*200 + kq*25 + m (m fastest). 3200 quads/step,
    // 12.5/thread -> 12 full + (tid<128) a 13th.
    const float* gp[13]; int woff[13];
#pragma unroll
    for (int i = 0; i < 13; ++i) {
        int Q = tid + 256 * i;
        if (Q < 3200) {
            int bb = Q / 200, r = Q - bb * 200;
            int kq = r / 25, m = r - kq * 25;
            gp[i]  = x + (size_t)(b0 + bb) * ROW_F + kq * 100 + m;
            woff[i] = (bb * 25 + m) * PITCH + kq * 4;
        } else { gp[i] = x; woff[i] = 0; }
    }

    float vbuf[13][4];
    auto issue = [&]() {          // next step's x -> regs (overlaps MFMA phase)
#pragma unroll
        for (int i = 0; i < 13; ++i) if (tid + 256 * i < 3200) {
#pragma unroll
            for (int j = 0; j < 4; ++j) vbuf[i][j] = gp[i][j * 25];
            gp[i] += 800;         // advance one K32-step (32*25 floats)
        }
    };
    auto scat = [&]() {           // 13 x ds_write_b64, <=2-way banked
#pragma unroll
        for (int i = 0; i < 13; ++i) if (tid + 256 * i < 3200) {
            ushortx4 h;
#pragma unroll
            for (int j = 0; j < 4; ++j) h[j] = f2bf(vbuf[i][j]);
            *reinterpret_cast<ushortx4*>(&Asm[woff[i]]) = h;
        }
    };

    floatx4 acc[25];
#pragma unroll
    for (int m = 0; m < 25; ++m) acc[m] = (floatx4){0.f, 0.f, 0.f, 0.f};

    issue();                      // stage step 0
#pragma unroll 1
    for (int s = 0; s < 16; ++s) {
        __syncthreads();          // previous step's A-reads done
        scat();                   // waits on vbuf vmcnt
        __syncthreads();          // tile visible
        if (s < 15) issue();      // next step's loads in flight under compute

        bf16x8v bfr[5];           // 5 l-deduped B-frags from L2 (16 lines/instr)
#pragma unroll
        for (int l = 0; l < 5; ++l)
            bfr[l] = *reinterpret_cast<const bf16x8v*>(
                wb + (size_t)(l * 512 + ow + lr) * 512 + s * 32 + lh * 8);
#pragma unroll
        for (int m = 0; m < 25; ++m) {
            const bf16x8v a = *reinterpret_cast<const bf16x8v*>(
                &Asm[(lr * 25 + m) * PITCH + lh * 8]);
            acc[m] = __builtin_amdgcn_mfma_f32_16x16x32_bf16(a, bfr[LOF[m]], acc[m], 0, 0, 0);
        }
    }

    // bias on the m=0 component only
    {
        float bv = bias[ow + lr];
#pragma unroll
        for (int r = 0; r < 4; ++r) acc[0][r] += bv;
    }

    // ---- LDS-staged epilogue: 4 passes x 4 b-rows; global stores = contiguous
    // 6.4KB float4 runs (r4's direct scatter doubled WRITE_SIZE - avoid).
    float* ep = reinterpret_cast<float*>(Asm);
    constexpr int EPROW = 1608;   // 1600 + 8 pad
#pragma unroll 1
    for (int p = 0; p < 4; ++p) {
        __syncthreads();          // k-loop reads / prior pass reads done
        if (lh == p) {            // D rows = lh*4 + r -> rows 4p..4p+3
#pragma unroll
            for (int m = 0; m < 25; ++m) {
                int cb = (wv * 16 + lr) * 25 + m;
#pragma unroll
                for (int r = 0; r < 4; ++r) ep[r * EPROW + cb] = acc[m][r];
            }
        }
        __syncthreads();
#pragma unroll 1
        for (int idx = tid; idx < 1600; idx += 256) {
            int rr = idx / 400, c4 = idx - rr * 400;
            floatx4 v = *reinterpret_cast<const floatx4*>(ep + rr * EPROW + c4 * 4);
            *reinterpret_cast<floatx4*>(
                out + (size_t)(b0 + p * 4 + rr) * ROW_F + o0 * 25 + c4 * 4) = v;
        }
    }
}

extern "C" void kernel_launch(void* const* d_in, const int* in_sizes, int n_in,
                              void* d_out, int out_size, void* d_ws, size_t ws_size,
                              hipStream_t stream) {
    const float* x    = (const float*)d_in[0];
    const float* w    = (const float*)d_in[1];
    const float* bias = (const float*)d_in[2];
    float* outp       = (float*)d_out;
    ushort_t* wb      = (ushort_t*)d_ws;    // 2.62 MB bf16 weights

    cvt_w_kernel<<<1280, 256, 0, stream>>>(w, wb);
    irrep_kernel<<<2048, 256, 0, stream>>>(x, wb, bias, outp);
}

// Round 7
// 289.011 us; speedup vs baseline: 2.0023x; 1.0158x over previous
//
#include <hip/hip_runtime.h>
#include <hip/hip_bf16.h>

// IrrepLinear: out[b, o*25+m] = sum_i x[b, i*25+m] * W[l(m), o, i]  (+bias at m=0)
// r6 = r5 + (a) sibling-coresident same-XCD block mapping (r5's FETCH was 800MB
// = 4x input because only 2/8 o-siblings of a btile were co-resident; now all 8
// share one XCD's L2 within a 64-bid dispatch window -> x fetched once) and
// (b) LDS pitch 40->44 ushorts (22 words, gcd(22,32)=2 -> staging writes hit
// 4 accesses/bank = ideal; reads stay 8/bank = ideal; r5 had 1.9e7 conflicts).

typedef __bf16 bf16x8v __attribute__((ext_vector_type(8)));
typedef float floatx4 __attribute__((ext_vector_type(4)));
typedef unsigned short ushort_t;
typedef unsigned short ushortx4 __attribute__((ext_vector_type(4)));

#define ROW_F 12800          // floats per batch row (512*25)
#define PITCH 44             // ushorts per LDS row: 32 k-data + 12 pad (88B)
#define LDS_USH (400 * 44)   // 35200 B -> 4 blocks/CU LDS-wise

__device__ __forceinline__ ushort_t f2bf(float f) {
    __hip_bfloat16 h = __float2bfloat16(f);   // RNE
    return __builtin_bit_cast(ushort_t, h);
}

// weight fp32 [5][512][512] -> bf16 in ws (same layout, k contiguous)
__global__ void cvt_w_kernel(const float* __restrict__ w, ushort_t* __restrict__ wb) {
    int i = (blockIdx.x * 256 + threadIdx.x) * 4;   // 1310720 elems, 1280x256 exact
    floatx4 v = *reinterpret_cast<const floatx4*>(w + i);
    ushortx4 h;
    h.x = f2bf(v[0]); h.y = f2bf(v[1]); h.z = f2bf(v[2]); h.w = f2bf(v[3]);
    *reinterpret_cast<ushortx4*>(wb + i) = h;
}

__global__ __launch_bounds__(256, 2) void irrep_kernel(
        const float* __restrict__ x, const ushort_t* __restrict__ wb,
        const float* __restrict__ bias, float* __restrict__ out) {
    __shared__ __align__(16) ushort_t Asm[LDS_USH];

    const int tid = threadIdx.x, lane = tid & 63;
    const int wv = tid >> 6;                  // 4 waves = 4 o-slices of 16
    const int lr = lane & 15, lh = lane >> 4;

    // Sibling-coresident same-XCD mapping: XCD = bid&7 = btile&7 for all 8
    // o-siblings; siblings' bids span only 64 -> co-dispatched. x window
    // (800KB) fetched from HBM once, 7/8 of reads L2-hit.
    const int bid   = blockIdx.x;             // 2048 blocks
    const int osib  = (bid >> 3) & 7;
    const int btile = (bid & 7) | ((bid >> 6) << 3);
    const int b0 = btile * 16, o0 = osib * 64, ow = o0 + wv * 16;

    constexpr int LOF[25] = {0,1,1,1,2,2,2,2,2,3,3,3,3,3,3,3,4,4,4,4,4,4,4,4,4};

    // ---- staging quads: Q = bb*200 + kq*25 + m (m fastest). 3200 quads/step,
    // 12.5/thread -> 12 full + (tid<128) a 13th.
    const float* gp[13]; int woff[13];
#pragma unroll
    for (int i = 0; i < 13; ++i) {
        int Q = tid + 256 * i;
        if (Q < 3200) {
            int bb = Q / 200, r = Q - bb * 200;
            int kq = r / 25, m = r - kq * 25;
            gp[i]  = x + (size_t)(b0 + bb) * ROW_F + kq * 100 + m;
            woff[i] = (bb * 25 + m) * PITCH + kq * 4;
        } else { gp[i] = x; woff[i] = 0; }
    }

    float vbuf[13][4];
    auto issue = [&]() {          // next step's x -> regs (overlaps MFMA phase)
#pragma unroll
        for (int i = 0; i < 13; ++i) if (tid + 256 * i < 3200) {
#pragma unroll
            for (int j = 0; j < 4; ++j) vbuf[i][j] = gp[i][j * 25];
            gp[i] += 800;         // advance one K32-step (32*25 floats)
        }
    };
    auto scat = [&]() {           // 13 x ds_write_b64, 4 accesses/bank (ideal)
#pragma unroll
        for (int i = 0; i < 13; ++i) if (tid + 256 * i < 3200) {
            ushortx4 h;
#pragma unroll
            for (int j = 0; j < 4; ++j) h[j] = f2bf(vbuf[i][j]);
            *reinterpret_cast<ushortx4*>(&Asm[woff[i]]) = h;
        }
    };

    floatx4 acc[25];
#pragma unroll
    for (int m = 0; m < 25; ++m) acc[m] = (floatx4){0.f, 0.f, 0.f, 0.f};

    issue();                      // stage step 0
#pragma unroll 1
    for (int s = 0; s < 16; ++s) {
        __syncthreads();          // previous step's A-reads done
        scat();                   // waits on vbuf vmcnt
        __syncthreads();          // tile visible
        if (s < 15) issue();      // next step's loads in flight under compute

        bf16x8v bfr[5];           // 5 l-deduped B-frags from L2
#pragma unroll
        for (int l = 0; l < 5; ++l)
            bfr[l] = *reinterpret_cast<const bf16x8v*>(
                wb + (size_t)(l * 512 + ow + lr) * 512 + s * 32 + lh * 8);
#pragma unroll
        for (int m = 0; m < 25; ++m) {
            const bf16x8v a = *reinterpret_cast<const bf16x8v*>(
                &Asm[(lr * 25 + m) * PITCH + lh * 8]);
            acc[m] = __builtin_amdgcn_mfma_f32_16x16x32_bf16(a, bfr[LOF[m]], acc[m], 0, 0, 0);
        }
    }

    // bias on the m=0 component only
    {
        float bv = bias[ow + lr];
#pragma unroll
        for (int r = 0; r < 4; ++r) acc[0][r] += bv;
    }

    // ---- LDS-staged epilogue: 4 passes x 4 b-rows; global stores = contiguous
    // 6.4KB float4 runs.
    float* ep = reinterpret_cast<float*>(Asm);
    constexpr int EPROW = 1608;   // 1600 + 8 pad
#pragma unroll 1
    for (int p = 0; p < 4; ++p) {
        __syncthreads();          // k-loop reads / prior pass reads done
        if (lh == p) {            // D rows = lh*4 + r -> rows 4p..4p+3
#pragma unroll
            for (int m = 0; m < 25; ++m) {
                int cb = (wv * 16 + lr) * 25 + m;
#pragma unroll
                for (int r = 0; r < 4; ++r) ep[r * EPROW + cb] = acc[m][r];
            }
        }
        __syncthreads();
#pragma unroll 1
        for (int idx = tid; idx < 1600; idx += 256) {
            int rr = idx / 400, c4 = idx - rr * 400;
            floatx4 v = *reinterpret_cast<const floatx4*>(ep + rr * EPROW + c4 * 4);
            *reinterpret_cast<floatx4*>(
                out + (size_t)(b0 + p * 4 + rr) * ROW_F + o0 * 25 + c4 * 4) = v;
        }
    }
}

extern "C" void kernel_launch(void* const* d_in, const int* in_sizes, int n_in,
                              void* d_out, int out_size, void* d_ws, size_t ws_size,
                              hipStream_t stream) {
    const float* x    = (const float*)d_in[0];
    const float* w    = (const float*)d_in[1];
    const float* bias = (const float*)d_in[2];
    float* outp       = (float*)d_out;
    ushort_t* wb      = (ushort_t*)d_ws;    // 2.62 MB bf16 weights

    cvt_w_kernel<<<1280, 256, 0, stream>>>(w, wb);
    irrep_kernel<<<2048, 256, 0, stream>>>(x, wb, bias, outp);
}